// Round 5
// baseline (165.249 us; speedup 1.0000x reference)
//
#include <hip/hip_runtime.h>
#include <math.h>

#define E_TYPES 20
#define NBLK 2
#define NANG 7
#define CS 384
#define CH 128
#define N_TOK (8 * 2048)
#define TOK 64
#define TPB_MAIN 512
#define KC 128
#define MAX_TILES (N_TOK / TOK + E_TYPES)   // 276
#define NPREP 64

// ---- workspace: int control region ----
#define HIST_OFF 0           // 64 x 20 per-block histograms

// ---- workspace: fragment-packed split-bf16 weights (bytes) ----
// 1KB block = 64 lanes x 16B; element (n,k): lane = (n&15)|((k>>3&3)<<4), j=k&7
#define WT1_OFF (256 * 1024)                       // phase-1 concat [768x128] per e
#define WT1_SZ  (20 * 8 * 24 * 2048)               // e x nt(8) x kb(24) x (hi1KB+lo1KB)
#define WTR_OFF (WT1_OFF + WT1_SZ)                 // residual: e x m4(4) x nt(8) x kb(4)
// total end ~13.4 MB

typedef __attribute__((ext_vector_type(8))) short bfrag;
typedef __attribute__((ext_vector_type(4))) float f32x4;
typedef unsigned short (*arr136)[136];

__device__ __forceinline__ void split_bf16(float x, unsigned short& h, unsigned short& l) {
    unsigned int u = __float_as_uint(x);
    unsigned int hb = (u + 0x7FFFu + ((u >> 16) & 1u)) & 0xFFFF0000u;
    h = (unsigned short)(hb >> 16);
    float r = x - __uint_as_float(hb);
    unsigned int v = __float_as_uint(r);
    l = (unsigned short)((v + 0x7FFFu + ((v >> 16) & 1u)) >> 16);
}

// prep1: blocks [0,1600) convert weights to fragment-packed split-bf16;
// blocks [1600,1664) build the per-block token histogram.
__global__ void prep1(const float* __restrict__ Win, const float* __restrict__ Winit,
                      const float* __restrict__ Wb1, const float* __restrict__ Wb2,
                      const int* __restrict__ aatype, int* __restrict__ wsI,
                      unsigned short* __restrict__ wt) {
    __shared__ int lh[E_TYPES];
    int bid = blockIdx.x;
    int t = threadIdx.x;
    if (bid >= 1600) {   // histogram part
        int b2 = bid - 1600;
        if (t < E_TYPES) lh[t] = 0;
        __syncthreads();
        int idx = b2 * 256 + t;
        if (idx < N_TOK) atomicAdd(&lh[aatype[idx]], 1);
        __syncthreads();
        if (t < E_TYPES) wsI[HIST_OFF + b2 * E_TYPES + t] = lh[t];
        return;
    }
    int gid = bid * 256 + t;
    unsigned short h[8], l[8];
    if (gid < 245760) {          // phase-1 weights: 20*8*24 blocks x 64 lanes
        int lane = gid & 63;
        int bi = gid >> 6;
        int kb = bi % 24;
        int r = bi / 24;
        int nt = r & 7, e = r >> 3;
        int n = nt * 16 + (lane & 15);
        int k0 = kb * 32 + (lane >> 4) * 8;
        #pragma unroll
        for (int j = 0; j < 8; j++) {
            int k = k0 + j;
            float x = (k < CS) ? Win[((size_t)e * CS + k) * CH + n]
                               : Winit[((size_t)e * CS + (k - CS)) * CH + n];
            split_bf16(x, h[j], l[j]);
        }
        unsigned short* dst = wt + (WT1_OFF / 2) + (size_t)bi * 1024 + lane * 8;
        *(bfrag*)dst = *(bfrag*)h;
        *(bfrag*)(dst + 512) = *(bfrag*)l;
    } else {                     // residual weights: 20*4*8*4 blocks x 64 lanes
        gid -= 245760;
        int lane = gid & 63;
        int bi = gid >> 6;       // 0..2559
        int kb = bi & 3;
        int nt = (bi >> 2) & 7;
        int m4 = (bi >> 5) & 3;
        int e = bi >> 7;
        int b = m4 >> 1;
        const float* W = (m4 & 1) ? Wb2 : Wb1;
        int n = nt * 16 + (lane & 15);
        int k0 = kb * 32 + (lane >> 4) * 8;
        #pragma unroll
        for (int j = 0; j < 8; j++) {
            int k = k0 + j;
            float x = W[(((size_t)e * NBLK + b) * CH + k) * CH + n];
            split_bf16(x, h[j], l[j]);
        }
        unsigned short* dst = wt + (WTR_OFF / 2) + (size_t)bi * 1024 + lane * 8;
        *(bfrag*)dst = *(bfrag*)h;
        *(bfrag*)(dst + 512) = *(bfrag*)l;
    }
}

#define MFMA(a, b, c) __builtin_amdgcn_mfma_f32_16x16x32_bf16((a), (b), (c), 0, 0, 0)

// Load the 8 weight fragments (bh ks0..3, bl ks0..3) for one stage.
#define LOADW(DST, BASEPTR) do {                                   \
    const bfrag* _p = (BASEPTR);                                   \
    DST[0] = _p[0];   DST[1] = _p[128];                            \
    DST[2] = _p[256]; DST[3] = _p[384];                            \
    DST[4] = _p[64];  DST[5] = _p[192];                            \
    DST[6] = _p[320]; DST[7] = _p[448];                            \
} while (0)

// One K=128 stage: 4 ks x 4 m-frags x 3 MFMA, A from LDS, B from CUR regs.
#define MFMA_STAGE(WAH, WAL, CUR, AA, BB) do {                     \
    _Pragma("unroll")                                              \
    for (int ks = 0; ks < 4; ks++) {                               \
        int kl = ks * 32 + quad * 8;                               \
        _Pragma("unroll")                                          \
        for (int m = 0; m < 4; m++) {                              \
            bfrag ah = *(const bfrag*)&WAH[m * 16 + lane15][kl];   \
            bfrag al = *(const bfrag*)&WAL[m * 16 + lane15][kl];   \
            AA[m] = MFMA(ah, CUR[ks], AA[m]);                      \
            BB[m] = MFMA(ah, CUR[4 + ks], BB[m]);                  \
            BB[m] = MFMA(al, CUR[ks], BB[m]);                      \
        }                                                          \
    }                                                              \
} while (0)

// Stage 16 fp32 regs (one K-chunk slice) as split-bf16 into LDS.
#define WRITE_A(WAH, WAL) do {                                     \
    float xv[16] = {p0.x, p0.y, p0.z, p0.w, p1.x, p1.y, p1.z, p1.w,\
                    p2.x, p2.y, p2.z, p2.w, p3.x, p3.y, p3.z, p3.w};\
    unsigned short h8[8], l8[8];                                   \
    _Pragma("unroll")                                              \
    for (int j = 0; j < 8; j++)                                    \
        split_bf16(fmaxf(xv[j], 0.f), h8[j], l8[j]);               \
    *(bfrag*)&WAH[srow][scol] = *(bfrag*)h8;                       \
    *(bfrag*)&WAL[srow][scol] = *(bfrag*)l8;                       \
    _Pragma("unroll")                                              \
    for (int j = 0; j < 8; j++)                                    \
        split_bf16(fmaxf(xv[8 + j], 0.f), h8[j], l8[j]);           \
    *(bfrag*)&WAH[srow][scol + 8] = *(bfrag*)h8;                   \
    *(bfrag*)&WAL[srow][scol + 8] = *(bfrag*)l8;                   \
} while (0)

// Write relu(SRC) (4 m-frags, C layout) as split-bf16 A for the next GEMM.
#define WRITE_H(WAH, WAL, SRC) do {                                \
    _Pragma("unroll")                                              \
    for (int m = 0; m < 4; m++)                                    \
    {                                                              \
        _Pragma("unroll")                                          \
        for (int rr = 0; rr < 4; rr++) {                           \
            unsigned short hh, ll;                                 \
            split_bf16(fmaxf(SRC[m][rr], 0.f), hh, ll);            \
            WAH[m * 16 + quad * 4 + rr][nc] = hh;                  \
            WAL[m * 16 + quad * 4 + rr][nc] = ll;                  \
        }                                                          \
    }                                                              \
} while (0)

// TOK=64, 512 thr (8 waves). Wave w owns N-strip w (16 cols) for ALL 64
// rows (4 m-frags). Key change vs prior rounds: 48 MFMAs per wave per
// stage now amortize the same 8 weight-fragment loads (was 12), fixing
// the exposed weight-load latency that paced every earlier variant.
__global__ __launch_bounds__(TPB_MAIN, 2)
void angle_main(const float* __restrict__ s, const float* __restrict__ si,
                const float* __restrict__ b_in, const float* __restrict__ b_init2,
                const float* __restrict__ bb1, const float* __restrict__ bb2,
                const float* __restrict__ Wout, const float* __restrict__ b_out,
                const int* __restrict__ aatype,
                const int* __restrict__ wsI, const unsigned short* __restrict__ wt,
                float* __restrict__ out)
{
    // LDS pool: two (Ah,Al) buffers of [64][136] u16; epilogue Hf/Of overlap.
    #define ABUF 17408
    __shared__ __align__(16) char pool[4 * ABUF];
    __shared__ int ptok[TOK];
    __shared__ int cntS[E_TYPES];

    arr136 AH0 = (arr136)(pool);
    arr136 AL0 = (arr136)(pool + ABUF);
    arr136 AH1 = (arr136)(pool + 2 * ABUF);
    arr136 AL1 = (arr136)(pool + 3 * ABUF);
    float (*Hf)[132] = (float (*)[132])(pool);            // 64*132*4 = 33792 <= 2*ABUF
    float (*Of)[16]  = (float (*)[16])(pool + 2 * ABUF);  // 4KB

    int t = threadIdx.x;
    int w = t >> 6, lane = t & 63;
    int lane15 = lane & 15, quad = lane >> 4;

    // XCD-chunked bijective swizzle (e-sorted tiles -> per-XCD L2 residency).
    int bid = blockIdx.x;
    const int q = MAX_TILES >> 3, r = MAX_TILES & 7;   // 34, 4
    int xcd = bid & 7, sub = bid >> 3;
    int tile = (xcd < r ? xcd * (q + 1) : r * (q + 1) + (xcd - r) * q) + sub;

    // wave0: per-type totals from the 64x20 chunk histograms
    if (w == 0 && lane < E_TYPES) {
        int c = 0;
        #pragma unroll
        for (int b = 0; b < NPREP; b++) c += wsI[HIST_OFF + b * E_TYPES + lane];
        cntS[lane] = c;
    }
    __syncthreads();

    int pos = tile * TOK;
    int e = -1, poff_e = 0;
    {
        int accT = 0;
        #pragma unroll
        for (int ee = 0; ee < E_TYPES; ee++) {
            int pad = (cntS[ee] + TOK - 1) & ~(TOK - 1);
            if (e < 0 && pos < accT + pad) { e = ee; poff_e = accT; }
            accT += pad;
        }
        if (pos >= accT) return;     // uniform exit (all waves agree)
    }
    int pos_in = pos - poff_e;
    int n = cntS[e] - pos_in; if (n > TOK) n = TOK;

    int nc = w * 16 + lane15;
    const bfrag* wt1 = (const bfrag*)((const char*)wt + WT1_OFF);
    const bfrag* wtr = (const bfrag*)((const char*)wt + WTR_OFF);
    size_t wb = (size_t)(e * 8 + w) * 24;

    // Early issue: stage-0 weights + all bias values (overlap the rank-scan).
    bfrag Wr0[8], Wr1[8];
    LOADW(Wr0, wt1 + wb * 128 + lane);
    float bv_in = b_in[e * CH + nc] + b_init2[e * CH + nc];
    float bvb1a = bb1[(e * NBLK + 0) * CH + nc];
    float bvb1b = bb1[(e * NBLK + 1) * CH + nc];
    float bvb2a = bb2[(e * NBLK + 0) * CH + nc];
    float bvb2b = bb2[(e * NBLK + 1) * CH + nc];

    // wave0: rank-scan aatype -> ptok (tokens with rank [pos_in, pos_in+n))
    if (w == 0) {
        int hb = wsI[HIST_OFF + lane * E_TYPES + e];
        int inc = hb;
        #pragma unroll
        for (int d = 1; d < 64; d <<= 1) { int v = __shfl_up(inc, d); if (lane >= d) inc += v; }
        int pre = inc - hb;
        unsigned long long mle = __ballot(pre <= pos_in);
        int cb = 63 - __clzll(mle);
        int running = __shfl(pre, cb);
        int base = cb * 256;
        int lim = pos_in + n;
        while (running < lim && base < N_TOK) {
            const int4 a4 = *(const int4*)&aatype[base + lane * 4];
            int m0 = (a4.x == e), m1 = (a4.y == e), m2 = (a4.z == e), m3 = (a4.w == e);
            int c = m0 + m1 + m2 + m3;
            int incl = c;
            #pragma unroll
            for (int d = 1; d < 64; d <<= 1) { int v = __shfl_up(incl, d); if (lane >= d) incl += v; }
            int rk = running + incl - c;
            int tk = base + lane * 4;
            if (m0) { if (rk >= pos_in && rk < lim) ptok[rk - pos_in] = tk;     rk++; }
            if (m1) { if (rk >= pos_in && rk < lim) ptok[rk - pos_in] = tk + 1; rk++; }
            if (m2) { if (rk >= pos_in && rk < lim) ptok[rk - pos_in] = tk + 2; rk++; }
            if (m3) { if (rk >= pos_in && rk < lim) ptok[rk - pos_in] = tk + 3; rk++; }
            running += __shfl(incl, 63);
            base += 256;
        }
        int t0 = ptok[0];
        if (lane >= n) ptok[lane] = t0;
    }
    __syncthreads();

    // ---- phase 1: h = [relu(s) relu(si)] @ [Win;Winit] + biases, K=768 ----
    // Staging: 8 threads/row x 16 floats (4 float4s), one chunk ahead in regs.
    int srow = t >> 3;
    int scol = (t & 7) * 16;
    size_t rowoff = (size_t)ptok[srow] * CS + scol;
    float4 p0 = *(const float4*)(s + rowoff);
    float4 p1 = *(const float4*)(s + rowoff + 4);
    float4 p2 = *(const float4*)(s + rowoff + 8);
    float4 p3 = *(const float4*)(s + rowoff + 12);

    f32x4 aA[4], aB[4];
    #pragma unroll
    for (int m = 0; m < 4; m++) {
        aA[m] = (f32x4){bv_in, bv_in, bv_in, bv_in};
        aB[m] = (f32x4){0.f, 0.f, 0.f, 0.f};
    }

    #pragma unroll
    for (int c = 0; c < 6; c++) {
        if ((c & 1) == 0) WRITE_A(AH0, AL0);
        else              WRITE_A(AH1, AL1);
        if (c < 5) {   // prefetch next chunk activations
            const float* src = (c + 1 < 3) ? s : si;
            int kb0 = ((c + 1 < 3) ? (c + 1) : (c - 2)) * KC;
            p0 = *(const float4*)(src + rowoff + kb0);
            p1 = *(const float4*)(src + rowoff + kb0 + 4);
            p2 = *(const float4*)(src + rowoff + kb0 + 8);
            p3 = *(const float4*)(src + rowoff + kb0 + 12);
        }
        __syncthreads();
        if ((c & 1) == 0) {
            if (c < 5) LOADW(Wr1, wt1 + (wb + (c + 1) * 4) * 128 + lane);
            MFMA_STAGE(AH0, AL0, Wr0, aA, aB);
        } else {
            if (c == 5) LOADW(Wr0, wtr + (((size_t)(e * 4) * 8 + w) * 4) * 128 + lane);
            else        LOADW(Wr0, wt1 + (wb + (c + 1) * 4) * 128 + lane);
            MFMA_STAGE(AH1, AL1, Wr1, aA, aB);
        }
    }

    // ---- residual blocks: 4 GEMMs, one barrier each ----
    f32x4 h[4];
    #pragma unroll
    for (int m = 0; m < 4; m++) h[m] = aA[m] + aB[m];
    WRITE_H(AH0, AL0, h);
    __syncthreads();

    f32x4 rA[4], rB[4];
    // g0: a1 = relu(h) @ W1[0] + bb1[0]
    #pragma unroll
    for (int m = 0; m < 4; m++) {
        rA[m] = (f32x4){bvb1a, bvb1a, bvb1a, bvb1a};
        rB[m] = (f32x4){0.f, 0.f, 0.f, 0.f};
    }
    LOADW(Wr1, wtr + (((size_t)(e * 4 + 1) * 8 + w) * 4) * 128 + lane);
    MFMA_STAGE(AH0, AL0, Wr0, rA, rB);
    #pragma unroll
    for (int m = 0; m < 4; m++) rA[m] += rB[m];
    WRITE_H(AH1, AL1, rA);
    __syncthreads();

    // g1: h += relu(a1) @ W2[0] + bb2[0]
    #pragma unroll
    for (int m = 0; m < 4; m++) {
        rA[m] = (f32x4){bvb2a, bvb2a, bvb2a, bvb2a};
        rB[m] = (f32x4){0.f, 0.f, 0.f, 0.f};
    }
    LOADW(Wr0, wtr + (((size_t)(e * 4 + 2) * 8 + w) * 4) * 128 + lane);
    MFMA_STAGE(AH1, AL1, Wr1, rA, rB);
    #pragma unroll
    for (int m = 0; m < 4; m++) h[m] += rA[m] + rB[m];
    WRITE_H(AH0, AL0, h);
    __syncthreads();

    // g2: a1 = relu(h) @ W1[1] + bb1[1]
    #pragma unroll
    for (int m = 0; m < 4; m++) {
        rA[m] = (f32x4){bvb1b, bvb1b, bvb1b, bvb1b};
        rB[m] = (f32x4){0.f, 0.f, 0.f, 0.f};
    }
    LOADW(Wr1, wtr + (((size_t)(e * 4 + 3) * 8 + w) * 4) * 128 + lane);
    MFMA_STAGE(AH0, AL0, Wr0, rA, rB);
    #pragma unroll
    for (int m = 0; m < 4; m++) rA[m] += rB[m];
    WRITE_H(AH1, AL1, rA);
    __syncthreads();

    // g3: h += relu(a1) @ W2[1] + bb2[1]
    #pragma unroll
    for (int m = 0; m < 4; m++) {
        rA[m] = (f32x4){bvb2b, bvb2b, bvb2b, bvb2b};
        rB[m] = (f32x4){0.f, 0.f, 0.f, 0.f};
    }
    MFMA_STAGE(AH1, AL1, Wr1, rA, rB);
    #pragma unroll
    for (int m = 0; m < 4; m++) h[m] += rA[m] + rB[m];

    // ---- epilogue: relu(h) fp32 -> Hf (buf0 region; g3 readers used buf1) ----
    #pragma unroll
    for (int m = 0; m < 4; m++)
    {
        #pragma unroll
        for (int rr = 0; rr < 4; rr++)
            Hf[m * 16 + quad * 4 + rr][nc] = fmaxf(h[m][rr], 0.f);
    }
    __syncthreads();

    // ---- out = relu(h) @ Wout + b_out (128 -> 14), 4-way partials ----
    const float* WoutE = Wout + (size_t)e * CH * (NANG * 2);
    const float* boutE = b_out + (size_t)e * (NANG * 2);
    for (int idx = t; idx < n * (NANG * 2); idx += TPB_MAIN) {
        int i = idx / (NANG * 2);
        int o = idx - i * (NANG * 2);
        float v0 = boutE[o], v1 = 0.f, v2 = 0.f, v3 = 0.f;
        #pragma unroll 4
        for (int k = 0; k < CH; k += 4) {
            v0 = fmaf(Hf[i][k],     WoutE[(size_t)k * (NANG * 2) + o],       v0);
            v1 = fmaf(Hf[i][k + 1], WoutE[(size_t)(k + 1) * (NANG * 2) + o], v1);
            v2 = fmaf(Hf[i][k + 2], WoutE[(size_t)(k + 2) * (NANG * 2) + o], v2);
            v3 = fmaf(Hf[i][k + 3], WoutE[(size_t)(k + 3) * (NANG * 2) + o], v3);
        }
        Of[i][o] = (v0 + v1) + (v2 + v3);
    }
    __syncthreads();

    // ---- pair-normalize and store ----
    for (int idx = t; idx < n * NANG; idx += TPB_MAIN) {
        int i = idx / NANG;
        int a = idx - i * NANG;
        float x = Of[i][2 * a];
        float y = Of[i][2 * a + 1];
        float nr = fmaxf(sqrtf(x * x + y * y), 1e-12f);
        size_t base = (size_t)ptok[i] * (NANG * 2) + 2 * a;
        out[base]     = x / nr;
        out[base + 1] = y / nr;
    }
}

extern "C" void kernel_launch(void* const* d_in, const int* in_sizes, int n_in,
                              void* d_out, int out_size, void* d_ws, size_t ws_size,
                              hipStream_t stream) {
    const float* s       = (const float*)d_in[0];
    const float* s_init  = (const float*)d_in[1];
    const int*   aatype  = (const int*)d_in[2];
    const float* Win     = (const float*)d_in[3];
    const float* b_in    = (const float*)d_in[4];
    const float* Winit   = (const float*)d_in[5];
    const float* b_init2 = (const float*)d_in[6];
    const float* Wb1     = (const float*)d_in[7];
    const float* bb1     = (const float*)d_in[8];
    const float* Wb2     = (const float*)d_in[9];
    const float* bb2     = (const float*)d_in[10];
    const float* Wout    = (const float*)d_in[11];
    const float* b_out   = (const float*)d_in[12];
    int* wsI = (int*)d_ws;
    unsigned short* wt = (unsigned short*)d_ws;
    float* out = (float*)d_out;

    hipLaunchKernelGGL(prep1, dim3(1664), dim3(256), 0, stream,
                       Win, Winit, Wb1, Wb2, aatype, wsI, wt);
    hipLaunchKernelGGL(angle_main, dim3(MAX_TILES), dim3(TPB_MAIN), 0, stream,
                       s, s_init, b_in, b_init2, bb1, bb2, Wout, b_out,
                       aatype, wsI, wt, out);
}

// Round 6
// 154.443 us; speedup vs baseline: 1.0700x; 1.0700x over previous
//
#include <hip/hip_runtime.h>
#include <math.h>

#define E_TYPES 20
#define NBLK 2
#define NANG 7
#define CS 384
#define CH 128
#define N_TOK (8 * 2048)
#define TOK 80
#define MFRAG 5
#define TPB_MAIN 512
#define KC 128
#define MAX_TILES (N_TOK / TOK + E_TYPES)   // 204 + 20 = 224 (provable upper bound)
#define NPREP 64

// ---- workspace: int control region ----
#define HIST_OFF 0           // 64 x 20 per-block histograms

// ---- workspace: fragment-packed split-bf16 weights (bytes) ----
// 1KB block = 64 lanes x 16B; element (n,k): lane = (n&15)|((k>>3&3)<<4), j=k&7
#define WT1_OFF (256 * 1024)                       // phase-1 concat [768x128] per e
#define WT1_SZ  (20 * 8 * 24 * 2048)               // e x nt(8) x kb(24) x (hi1KB+lo1KB)
#define WTR_OFF (WT1_OFF + WT1_SZ)                 // residual: e x m4(4) x nt(8) x kb(4)
// total end ~13.4 MB

typedef __attribute__((ext_vector_type(8))) short bfrag;
typedef __attribute__((ext_vector_type(4))) float f32x4;
typedef unsigned short (*arr136)[136];

__device__ __forceinline__ void split_bf16(float x, unsigned short& h, unsigned short& l) {
    unsigned int u = __float_as_uint(x);
    unsigned int hb = (u + 0x7FFFu + ((u >> 16) & 1u)) & 0xFFFF0000u;
    h = (unsigned short)(hb >> 16);
    float r = x - __uint_as_float(hb);
    unsigned int v = __float_as_uint(r);
    l = (unsigned short)((v + 0x7FFFu + ((v >> 16) & 1u)) >> 16);
}

// prep1: blocks [0,1600) convert weights to fragment-packed split-bf16;
// blocks [1600,1664) build the per-block token histogram.
__global__ void prep1(const float* __restrict__ Win, const float* __restrict__ Winit,
                      const float* __restrict__ Wb1, const float* __restrict__ Wb2,
                      const int* __restrict__ aatype, int* __restrict__ wsI,
                      unsigned short* __restrict__ wt) {
    __shared__ int lh[E_TYPES];
    int bid = blockIdx.x;
    int t = threadIdx.x;
    if (bid >= 1600) {   // histogram part
        int b2 = bid - 1600;
        if (t < E_TYPES) lh[t] = 0;
        __syncthreads();
        int idx = b2 * 256 + t;
        if (idx < N_TOK) atomicAdd(&lh[aatype[idx]], 1);
        __syncthreads();
        if (t < E_TYPES) wsI[HIST_OFF + b2 * E_TYPES + t] = lh[t];
        return;
    }
    int gid = bid * 256 + t;
    unsigned short h[8], l[8];
    if (gid < 245760) {          // phase-1 weights: 20*8*24 blocks x 64 lanes
        int lane = gid & 63;
        int bi = gid >> 6;
        int kb = bi % 24;
        int r = bi / 24;
        int nt = r & 7, e = r >> 3;
        int n = nt * 16 + (lane & 15);
        int k0 = kb * 32 + (lane >> 4) * 8;
        #pragma unroll
        for (int j = 0; j < 8; j++) {
            int k = k0 + j;
            float x = (k < CS) ? Win[((size_t)e * CS + k) * CH + n]
                               : Winit[((size_t)e * CS + (k - CS)) * CH + n];
            split_bf16(x, h[j], l[j]);
        }
        unsigned short* dst = wt + (WT1_OFF / 2) + (size_t)bi * 1024 + lane * 8;
        *(bfrag*)dst = *(bfrag*)h;
        *(bfrag*)(dst + 512) = *(bfrag*)l;
    } else {                     // residual weights: 20*4*8*4 blocks x 64 lanes
        gid -= 245760;
        int lane = gid & 63;
        int bi = gid >> 6;       // 0..2559
        int kb = bi & 3;
        int nt = (bi >> 2) & 7;
        int m4 = (bi >> 5) & 3;
        int e = bi >> 7;
        int b = m4 >> 1;
        const float* W = (m4 & 1) ? Wb2 : Wb1;
        int n = nt * 16 + (lane & 15);
        int k0 = kb * 32 + (lane >> 4) * 8;
        #pragma unroll
        for (int j = 0; j < 8; j++) {
            int k = k0 + j;
            float x = W[(((size_t)e * NBLK + b) * CH + k) * CH + n];
            split_bf16(x, h[j], l[j]);
        }
        unsigned short* dst = wt + (WTR_OFF / 2) + (size_t)bi * 1024 + lane * 8;
        *(bfrag*)dst = *(bfrag*)h;
        *(bfrag*)(dst + 512) = *(bfrag*)l;
    }
}

#define MFMA(a, b, c) __builtin_amdgcn_mfma_f32_16x16x32_bf16((a), (b), (c), 0, 0, 0)

// Load the 8 weight fragments (bh ks0..3, bl ks0..3) for one stage.
#define LOADW(DST, BASEPTR) do {                                   \
    const bfrag* _p = (BASEPTR);                                   \
    DST[0] = _p[0];   DST[1] = _p[128];                            \
    DST[2] = _p[256]; DST[3] = _p[384];                            \
    DST[4] = _p[64];  DST[5] = _p[192];                            \
    DST[6] = _p[320]; DST[7] = _p[448];                            \
} while (0)

// One K=128 stage: 4 ks x 5 m-frags x 3 MFMA, A from LDS, B from CUR regs.
#define MFMA_STAGE(WAH, WAL, CUR, AA, BB) do {                     \
    _Pragma("unroll")                                              \
    for (int ks = 0; ks < 4; ks++) {                               \
        int kl = ks * 32 + quad * 8;                               \
        _Pragma("unroll")                                          \
        for (int m = 0; m < MFRAG; m++) {                          \
            bfrag ah = *(const bfrag*)&WAH[m * 16 + lane15][kl];   \
            bfrag al = *(const bfrag*)&WAL[m * 16 + lane15][kl];   \
            AA[m] = MFMA(ah, CUR[ks], AA[m]);                      \
            BB[m] = MFMA(ah, CUR[4 + ks], BB[m]);                  \
            BB[m] = MFMA(al, CUR[ks], BB[m]);                      \
        }                                                          \
    }                                                              \
} while (0)

// Write relu(SRC) (MFRAG m-frags, C layout) as split-bf16 A for next GEMM.
#define WRITE_H(WAH, WAL, SRC) do {                                \
    _Pragma("unroll")                                              \
    for (int m = 0; m < MFRAG; m++)                                \
    {                                                              \
        _Pragma("unroll")                                          \
        for (int rr = 0; rr < 4; rr++) {                           \
            unsigned short hh, ll;                                 \
            split_bf16(fmaxf(SRC[m][rr], 0.f), hh, ll);            \
            WAH[m * 16 + quad * 4 + rr][nc] = hh;                  \
            WAL[m * 16 + quad * 4 + rr][nc] = ll;                  \
        }                                                          \
    }                                                              \
} while (0)

// Stage one 16-float activation segment (relu + split) into LDS.
__device__ __forceinline__ void stage_seg(arr136 WAH, arr136 WAL, int row, int col,
                                          float4 a, float4 b, float4 c, float4 d) {
    float xv[16] = {a.x, a.y, a.z, a.w, b.x, b.y, b.z, b.w,
                    c.x, c.y, c.z, c.w, d.x, d.y, d.z, d.w};
    unsigned short h8[8], l8[8];
    #pragma unroll
    for (int j = 0; j < 8; j++) split_bf16(fmaxf(xv[j], 0.f), h8[j], l8[j]);
    *(bfrag*)&WAH[row][col] = *(bfrag*)h8;
    *(bfrag*)&WAL[row][col] = *(bfrag*)l8;
    #pragma unroll
    for (int j = 0; j < 8; j++) split_bf16(fmaxf(xv[8 + j], 0.f), h8[j], l8[j]);
    *(bfrag*)&WAH[row][col + 8] = *(bfrag*)h8;
    *(bfrag*)&WAL[row][col + 8] = *(bfrag*)l8;
}

// TOK=80 (5 m-frags): tile count <= 224 <= 256 for ANY type distribution,
// so every block runs in the first (and only) wave of blocks per CU.
// This removes the serial tail that paced rounds 2-5 (20 CUs running
// ceil(tiles/256) blocks back-to-back while the rest idled = ~2x kernel
// time). Body is the round-5 structure unchanged otherwise.
__global__ __launch_bounds__(TPB_MAIN, 2)
void angle_main(const float* __restrict__ s, const float* __restrict__ si,
                const float* __restrict__ b_in, const float* __restrict__ b_init2,
                const float* __restrict__ bb1, const float* __restrict__ bb2,
                const float* __restrict__ Wout, const float* __restrict__ b_out,
                const int* __restrict__ aatype,
                const int* __restrict__ wsI, const unsigned short* __restrict__ wt,
                float* __restrict__ out)
{
    // LDS pool: two (Ah,Al) buffers of [80][136] u16; epilogue Hf/Of overlap.
    #define ABUF 21760
    __shared__ __align__(16) char pool[4 * ABUF];
    __shared__ int ptok[TOK];
    __shared__ int cntS[E_TYPES];

    arr136 AH0 = (arr136)(pool);
    arr136 AL0 = (arr136)(pool + ABUF);
    arr136 AH1 = (arr136)(pool + 2 * ABUF);
    arr136 AL1 = (arr136)(pool + 3 * ABUF);
    float (*Hf)[132] = (float (*)[132])(pool);            // 80*132*4 = 42240 <= 2*ABUF
    float (*Of)[16]  = (float (*)[16])(pool + 2 * ABUF);  // 5KB

    int t = threadIdx.x;
    int w = t >> 6, lane = t & 63;
    int lane15 = lane & 15, quad = lane >> 4;

    // XCD-chunked bijective swizzle (e-sorted tiles -> per-XCD L2 residency).
    int bid = blockIdx.x;
    const int q = MAX_TILES >> 3, r = MAX_TILES & 7;   // 28, 0
    int xcd = bid & 7, sub = bid >> 3;
    int tile = (xcd < r ? xcd * (q + 1) : r * (q + 1) + (xcd - r) * q) + sub;

    // wave0: per-type totals from the 64x20 chunk histograms
    if (w == 0 && lane < E_TYPES) {
        int c = 0;
        #pragma unroll
        for (int b = 0; b < NPREP; b++) c += wsI[HIST_OFF + b * E_TYPES + lane];
        cntS[lane] = c;
    }
    __syncthreads();

    int pos = tile * TOK;
    int e = -1, poff_e = 0;
    {
        int accT = 0;
        #pragma unroll
        for (int ee = 0; ee < E_TYPES; ee++) {
            int pad = ((cntS[ee] + TOK - 1) / TOK) * TOK;   // TOK not pow2
            if (e < 0 && pos < accT + pad) { e = ee; poff_e = accT; }
            accT += pad;
        }
        if (pos >= accT) return;     // uniform exit (all waves agree)
    }
    int pos_in = pos - poff_e;
    int n = cntS[e] - pos_in; if (n > TOK) n = TOK;

    int nc = w * 16 + lane15;
    const bfrag* wt1 = (const bfrag*)((const char*)wt + WT1_OFF);
    const bfrag* wtr = (const bfrag*)((const char*)wt + WTR_OFF);
    size_t wb = (size_t)(e * 8 + w) * 24;

    // Early issue: stage-0 weights + all bias values (overlap the rank-scan).
    bfrag Wr0[8], Wr1[8];
    LOADW(Wr0, wt1 + wb * 128 + lane);
    float bv_in = b_in[e * CH + nc] + b_init2[e * CH + nc];
    float bvb1a = bb1[(e * NBLK + 0) * CH + nc];
    float bvb1b = bb1[(e * NBLK + 1) * CH + nc];
    float bvb2a = bb2[(e * NBLK + 0) * CH + nc];
    float bvb2b = bb2[(e * NBLK + 1) * CH + nc];

    // wave0: rank-scan aatype -> ptok (tokens with rank [pos_in, pos_in+n))
    if (w == 0) {
        int hb = wsI[HIST_OFF + lane * E_TYPES + e];
        int inc = hb;
        #pragma unroll
        for (int d = 1; d < 64; d <<= 1) { int v = __shfl_up(inc, d); if (lane >= d) inc += v; }
        int pre = inc - hb;
        unsigned long long mle = __ballot(pre <= pos_in);
        int cb = 63 - __clzll(mle);
        int running = __shfl(pre, cb);
        int base = cb * 256;
        int lim = pos_in + n;
        while (running < lim && base < N_TOK) {
            const int4 a4 = *(const int4*)&aatype[base + lane * 4];
            int m0 = (a4.x == e), m1 = (a4.y == e), m2 = (a4.z == e), m3 = (a4.w == e);
            int c = m0 + m1 + m2 + m3;
            int incl = c;
            #pragma unroll
            for (int d = 1; d < 64; d <<= 1) { int v = __shfl_up(incl, d); if (lane >= d) incl += v; }
            int rk = running + incl - c;
            int tk = base + lane * 4;
            if (m0) { if (rk >= pos_in && rk < lim) ptok[rk - pos_in] = tk;     rk++; }
            if (m1) { if (rk >= pos_in && rk < lim) ptok[rk - pos_in] = tk + 1; rk++; }
            if (m2) { if (rk >= pos_in && rk < lim) ptok[rk - pos_in] = tk + 2; rk++; }
            if (m3) { if (rk >= pos_in && rk < lim) ptok[rk - pos_in] = tk + 3; rk++; }
            running += __shfl(incl, 63);
            base += 256;
        }
        int t0v = ptok[0];
        for (int i = n + lane; i < TOK; i += 64) ptok[i] = t0v;   // pad w/ dup token
    }
    __syncthreads();

    // ---- phase 1: h = [relu(s) relu(si)] @ [Win;Winit] + biases, K=768 ----
    // Staging: 640 segs (80 rows x 8) over 512 threads; waves 0-1 take a
    // second seg (wave-uniform). One chunk prefetched ahead in regs.
    int srow0 = t >> 3;
    int scol0 = (t & 7) * 16;
    bool has2 = (t < TOK * 8 - TPB_MAIN);    // t < 128
    int srow1 = srow0 + 64;
    size_t ro0 = (size_t)ptok[srow0] * CS + scol0;
    size_t ro1 = has2 ? ((size_t)ptok[srow1] * CS + scol0) : ro0;
    float4 p0 = *(const float4*)(s + ro0);
    float4 p1 = *(const float4*)(s + ro0 + 4);
    float4 p2 = *(const float4*)(s + ro0 + 8);
    float4 p3 = *(const float4*)(s + ro0 + 12);
    float4 q0, q1, q2, q3;
    if (has2) {
        q0 = *(const float4*)(s + ro1);
        q1 = *(const float4*)(s + ro1 + 4);
        q2 = *(const float4*)(s + ro1 + 8);
        q3 = *(const float4*)(s + ro1 + 12);
    }

    f32x4 aA[MFRAG], aB[MFRAG];
    #pragma unroll
    for (int m = 0; m < MFRAG; m++) {
        aA[m] = (f32x4){bv_in, bv_in, bv_in, bv_in};
        aB[m] = (f32x4){0.f, 0.f, 0.f, 0.f};
    }

    #pragma unroll
    for (int c = 0; c < 6; c++) {
        arr136 WAH = (c & 1) ? AH1 : AH0;
        arr136 WAL = (c & 1) ? AL1 : AL0;
        stage_seg(WAH, WAL, srow0, scol0, p0, p1, p2, p3);
        if (has2) stage_seg(WAH, WAL, srow1, scol0, q0, q1, q2, q3);
        if (c < 5) {   // prefetch next chunk activations
            const float* src = (c + 1 < 3) ? s : si;
            int kb0 = ((c + 1 < 3) ? (c + 1) : (c - 2)) * KC;
            p0 = *(const float4*)(src + ro0 + kb0);
            p1 = *(const float4*)(src + ro0 + kb0 + 4);
            p2 = *(const float4*)(src + ro0 + kb0 + 8);
            p3 = *(const float4*)(src + ro0 + kb0 + 12);
            if (has2) {
                q0 = *(const float4*)(src + ro1 + kb0);
                q1 = *(const float4*)(src + ro1 + kb0 + 4);
                q2 = *(const float4*)(src + ro1 + kb0 + 8);
                q3 = *(const float4*)(src + ro1 + kb0 + 12);
            }
        }
        __syncthreads();
        if ((c & 1) == 0) {
            if (c < 5) LOADW(Wr1, wt1 + (wb + (c + 1) * 4) * 128 + lane);
            MFMA_STAGE(AH0, AL0, Wr0, aA, aB);
        } else {
            if (c == 5) LOADW(Wr0, wtr + (((size_t)(e * 4) * 8 + w) * 4) * 128 + lane);
            else        LOADW(Wr0, wt1 + (wb + (c + 1) * 4) * 128 + lane);
            MFMA_STAGE(AH1, AL1, Wr1, aA, aB);
        }
    }

    // ---- residual blocks: 4 GEMMs, one barrier each ----
    f32x4 h[MFRAG];
    #pragma unroll
    for (int m = 0; m < MFRAG; m++) h[m] = aA[m] + aB[m];
    WRITE_H(AH0, AL0, h);
    __syncthreads();

    f32x4 rA[MFRAG], rB[MFRAG];
    // g0: a1 = relu(h) @ W1[0] + bb1[0]
    #pragma unroll
    for (int m = 0; m < MFRAG; m++) {
        rA[m] = (f32x4){bvb1a, bvb1a, bvb1a, bvb1a};
        rB[m] = (f32x4){0.f, 0.f, 0.f, 0.f};
    }
    LOADW(Wr1, wtr + (((size_t)(e * 4 + 1) * 8 + w) * 4) * 128 + lane);
    MFMA_STAGE(AH0, AL0, Wr0, rA, rB);
    #pragma unroll
    for (int m = 0; m < MFRAG; m++) rA[m] += rB[m];
    WRITE_H(AH1, AL1, rA);
    __syncthreads();

    // g1: h += relu(a1) @ W2[0] + bb2[0]
    #pragma unroll
    for (int m = 0; m < MFRAG; m++) {
        rA[m] = (f32x4){bvb2a, bvb2a, bvb2a, bvb2a};
        rB[m] = (f32x4){0.f, 0.f, 0.f, 0.f};
    }
    LOADW(Wr0, wtr + (((size_t)(e * 4 + 2) * 8 + w) * 4) * 128 + lane);
    MFMA_STAGE(AH1, AL1, Wr1, rA, rB);
    #pragma unroll
    for (int m = 0; m < MFRAG; m++) h[m] += rA[m] + rB[m];
    WRITE_H(AH0, AL0, h);
    __syncthreads();

    // g2: a1 = relu(h) @ W1[1] + bb1[1]
    #pragma unroll
    for (int m = 0; m < MFRAG; m++) {
        rA[m] = (f32x4){bvb1b, bvb1b, bvb1b, bvb1b};
        rB[m] = (f32x4){0.f, 0.f, 0.f, 0.f};
    }
    LOADW(Wr1, wtr + (((size_t)(e * 4 + 3) * 8 + w) * 4) * 128 + lane);
    MFMA_STAGE(AH0, AL0, Wr0, rA, rB);
    #pragma unroll
    for (int m = 0; m < MFRAG; m++) rA[m] += rB[m];
    WRITE_H(AH1, AL1, rA);
    __syncthreads();

    // g3: h += relu(a1) @ W2[1] + bb2[1]
    #pragma unroll
    for (int m = 0; m < MFRAG; m++) {
        rA[m] = (f32x4){bvb2b, bvb2b, bvb2b, bvb2b};
        rB[m] = (f32x4){0.f, 0.f, 0.f, 0.f};
    }
    MFMA_STAGE(AH1, AL1, Wr1, rA, rB);
    #pragma unroll
    for (int m = 0; m < MFRAG; m++) h[m] += rA[m] + rB[m];

    // ---- epilogue: relu(h) fp32 -> Hf (buf0 region; g3 readers used buf1) ----
    #pragma unroll
    for (int m = 0; m < MFRAG; m++)
    {
        #pragma unroll
        for (int rr = 0; rr < 4; rr++)
            Hf[m * 16 + quad * 4 + rr][nc] = fmaxf(h[m][rr], 0.f);
    }
    __syncthreads();

    // ---- out = relu(h) @ Wout + b_out (128 -> 14), 4-way partials ----
    const float* WoutE = Wout + (size_t)e * CH * (NANG * 2);
    const float* boutE = b_out + (size_t)e * (NANG * 2);
    for (int idx = t; idx < n * (NANG * 2); idx += TPB_MAIN) {
        int i = idx / (NANG * 2);
        int o = idx - i * (NANG * 2);
        float v0 = boutE[o], v1 = 0.f, v2 = 0.f, v3 = 0.f;
        #pragma unroll 4
        for (int k = 0; k < CH; k += 4) {
            v0 = fmaf(Hf[i][k],     WoutE[(size_t)k * (NANG * 2) + o],       v0);
            v1 = fmaf(Hf[i][k + 1], WoutE[(size_t)(k + 1) * (NANG * 2) + o], v1);
            v2 = fmaf(Hf[i][k + 2], WoutE[(size_t)(k + 2) * (NANG * 2) + o], v2);
            v3 = fmaf(Hf[i][k + 3], WoutE[(size_t)(k + 3) * (NANG * 2) + o], v3);
        }
        Of[i][o] = (v0 + v1) + (v2 + v3);
    }
    __syncthreads();

    // ---- pair-normalize and store ----
    for (int idx = t; idx < n * NANG; idx += TPB_MAIN) {
        int i = idx / NANG;
        int a = idx - i * NANG;
        float x = Of[i][2 * a];
        float y = Of[i][2 * a + 1];
        float nr = fmaxf(sqrtf(x * x + y * y), 1e-12f);
        size_t base = (size_t)ptok[i] * (NANG * 2) + 2 * a;
        out[base]     = x / nr;
        out[base + 1] = y / nr;
    }
}

extern "C" void kernel_launch(void* const* d_in, const int* in_sizes, int n_in,
                              void* d_out, int out_size, void* d_ws, size_t ws_size,
                              hipStream_t stream) {
    const float* s       = (const float*)d_in[0];
    const float* s_init  = (const float*)d_in[1];
    const int*   aatype  = (const int*)d_in[2];
    const float* Win     = (const float*)d_in[3];
    const float* b_in    = (const float*)d_in[4];
    const float* Winit   = (const float*)d_in[5];
    const float* b_init2 = (const float*)d_in[6];
    const float* Wb1     = (const float*)d_in[7];
    const float* bb1     = (const float*)d_in[8];
    const float* Wb2     = (const float*)d_in[9];
    const float* bb2     = (const float*)d_in[10];
    const float* Wout    = (const float*)d_in[11];
    const float* b_out   = (const float*)d_in[12];
    int* wsI = (int*)d_ws;
    unsigned short* wt = (unsigned short*)d_ws;
    float* out = (float*)d_out;

    hipLaunchKernelGGL(prep1, dim3(1664), dim3(256), 0, stream,
                       Win, Winit, Wb1, Wb2, aatype, wsI, wt);
    hipLaunchKernelGGL(angle_main, dim3(MAX_TILES), dim3(TPB_MAIN), 0, stream,
                       s, s_init, b_in, b_init2, bb1, bb2, Wout, b_out,
                       aatype, wsI, wt, out);
}

// Round 7
// 153.826 us; speedup vs baseline: 1.0743x; 1.0040x over previous
//
#include <hip/hip_runtime.h>
#include <math.h>

#define E_TYPES 20
#define NBLK 2
#define NANG 7
#define CS 384
#define CH 128
#define N_TOK (8 * 2048)
#define TOK 80
#define MFRAG 5
#define TPB_MAIN 512
#define KC 128
#define MAX_TILES (N_TOK / TOK + E_TYPES)   // 204 + 20 = 224 (provable upper bound)
#define NPREP 64

// ---- workspace: int control region ----
#define HIST_OFF 0           // 64 x 20 per-block histograms

// ---- workspace: fragment-packed split-bf16 weights (bytes) ----
// 1KB block = 64 lanes x 16B; element (n,k): lane = (n&15)|((k>>3&3)<<4), j=k&7
#define WT1_OFF (256 * 1024)                       // phase-1 concat [768x128] per e
#define WT1_SZ  (20 * 8 * 24 * 2048)               // e x nt(8) x kb(24) x (hi1KB+lo1KB)
#define WTR_OFF (WT1_OFF + WT1_SZ)                 // residual: e x m4(4) x nt(8) x kb(4)
// total end ~13.4 MB

typedef __attribute__((ext_vector_type(8))) short bfrag;
typedef __attribute__((ext_vector_type(4))) float f32x4;
typedef unsigned short (*arr136)[136];

__device__ __forceinline__ void split_bf16(float x, unsigned short& h, unsigned short& l) {
    unsigned int u = __float_as_uint(x);
    unsigned int hb = (u + 0x7FFFu + ((u >> 16) & 1u)) & 0xFFFF0000u;
    h = (unsigned short)(hb >> 16);
    float r = x - __uint_as_float(hb);
    unsigned int v = __float_as_uint(r);
    l = (unsigned short)((v + 0x7FFFu + ((v >> 16) & 1u)) >> 16);
}

// prep1: blocks [0,1600) convert weights to fragment-packed split-bf16;
// blocks [1600,1664) build the per-block token histogram.
__global__ void prep1(const float* __restrict__ Win, const float* __restrict__ Winit,
                      const float* __restrict__ Wb1, const float* __restrict__ Wb2,
                      const int* __restrict__ aatype, int* __restrict__ wsI,
                      unsigned short* __restrict__ wt) {
    __shared__ int lh[E_TYPES];
    int bid = blockIdx.x;
    int t = threadIdx.x;
    if (bid >= 1600) {   // histogram part
        int b2 = bid - 1600;
        if (t < E_TYPES) lh[t] = 0;
        __syncthreads();
        int idx = b2 * 256 + t;
        if (idx < N_TOK) atomicAdd(&lh[aatype[idx]], 1);
        __syncthreads();
        if (t < E_TYPES) wsI[HIST_OFF + b2 * E_TYPES + t] = lh[t];
        return;
    }
    int gid = bid * 256 + t;
    unsigned short h[8], l[8];
    if (gid < 245760) {          // phase-1 weights: 20*8*24 blocks x 64 lanes
        int lane = gid & 63;
        int bi = gid >> 6;
        int kb = bi % 24;
        int r = bi / 24;
        int nt = r & 7, e = r >> 3;
        int n = nt * 16 + (lane & 15);
        int k0 = kb * 32 + (lane >> 4) * 8;
        #pragma unroll
        for (int j = 0; j < 8; j++) {
            int k = k0 + j;
            float x = (k < CS) ? Win[((size_t)e * CS + k) * CH + n]
                               : Winit[((size_t)e * CS + (k - CS)) * CH + n];
            split_bf16(x, h[j], l[j]);
        }
        unsigned short* dst = wt + (WT1_OFF / 2) + (size_t)bi * 1024 + lane * 8;
        *(bfrag*)dst = *(bfrag*)h;
        *(bfrag*)(dst + 512) = *(bfrag*)l;
    } else {                     // residual weights: 20*4*8*4 blocks x 64 lanes
        gid -= 245760;
        int lane = gid & 63;
        int bi = gid >> 6;       // 0..2559
        int kb = bi & 3;
        int nt = (bi >> 2) & 7;
        int m4 = (bi >> 5) & 3;
        int e = bi >> 7;
        int b = m4 >> 1;
        const float* W = (m4 & 1) ? Wb2 : Wb1;
        int n = nt * 16 + (lane & 15);
        int k0 = kb * 32 + (lane >> 4) * 8;
        #pragma unroll
        for (int j = 0; j < 8; j++) {
            int k = k0 + j;
            float x = W[(((size_t)e * NBLK + b) * CH + k) * CH + n];
            split_bf16(x, h[j], l[j]);
        }
        unsigned short* dst = wt + (WTR_OFF / 2) + (size_t)bi * 1024 + lane * 8;
        *(bfrag*)dst = *(bfrag*)h;
        *(bfrag*)(dst + 512) = *(bfrag*)l;
    }
}

#define MFMA(a, b, c) __builtin_amdgcn_mfma_f32_16x16x32_bf16((a), (b), (c), 0, 0, 0)

// Load the 8 weight fragments (bh ks0..3, bl ks0..3) for one stage.
#define LOADW(DST, BASEPTR) do {                                   \
    const bfrag* _p = (BASEPTR);                                   \
    DST[0] = _p[0];   DST[1] = _p[128];                            \
    DST[2] = _p[256]; DST[3] = _p[384];                            \
    DST[4] = _p[64];  DST[5] = _p[192];                            \
    DST[6] = _p[320]; DST[7] = _p[448];                            \
} while (0)

// One K=128 stage, register-pipelined: batch-load all 10 A-fragments of
// k-slice ks into a double-buffered reg array, issuing slice ks+1's reads
// BEFORE slice ks's 15 MFMAs. All indices compile-time after unroll.
// (Prior version read 2 frags per 3 MFMAs -> compiler held only ~2 reads
// in flight at VGPR=96 -> ~120cy LDS latency exposed per pair, ~20x/stage.)
#define MFMA_STAGE(WAH, WAL, CUR, AA, BB) do {                     \
    bfrag fh[2][MFRAG], fl[2][MFRAG];                              \
    _Pragma("unroll")                                              \
    for (int m = 0; m < MFRAG; m++) {                              \
        fh[0][m] = *(const bfrag*)&WAH[m * 16 + lane15][quad * 8]; \
        fl[0][m] = *(const bfrag*)&WAL[m * 16 + lane15][quad * 8]; \
    }                                                              \
    _Pragma("unroll")                                              \
    for (int ks = 0; ks < 4; ks++) {                               \
        if (ks < 3) {                                              \
            int nkl = (ks + 1) * 32 + quad * 8;                    \
            _Pragma("unroll")                                      \
            for (int m = 0; m < MFRAG; m++) {                      \
                fh[(ks + 1) & 1][m] = *(const bfrag*)&WAH[m * 16 + lane15][nkl]; \
                fl[(ks + 1) & 1][m] = *(const bfrag*)&WAL[m * 16 + lane15][nkl]; \
            }                                                      \
        }                                                          \
        _Pragma("unroll")                                          \
        for (int m = 0; m < MFRAG; m++) {                          \
            AA[m] = MFMA(fh[ks & 1][m], CUR[ks], AA[m]);           \
            BB[m] = MFMA(fh[ks & 1][m], CUR[4 + ks], BB[m]);       \
            BB[m] = MFMA(fl[ks & 1][m], CUR[ks], BB[m]);           \
        }                                                          \
    }                                                              \
} while (0)

// Write relu(SRC) (MFRAG m-frags, C layout) as split-bf16 A for next GEMM.
#define WRITE_H(WAH, WAL, SRC) do {                                \
    _Pragma("unroll")                                              \
    for (int m = 0; m < MFRAG; m++)                                \
    {                                                              \
        _Pragma("unroll")                                          \
        for (int rr = 0; rr < 4; rr++) {                           \
            unsigned short hh, ll;                                 \
            split_bf16(fmaxf(SRC[m][rr], 0.f), hh, ll);            \
            WAH[m * 16 + quad * 4 + rr][nc] = hh;                  \
            WAL[m * 16 + quad * 4 + rr][nc] = ll;                  \
        }                                                          \
    }                                                              \
} while (0)

// Stage one 16-float activation segment (relu + split) into LDS.
__device__ __forceinline__ void stage_seg(arr136 WAH, arr136 WAL, int row, int col,
                                          float4 a, float4 b, float4 c, float4 d) {
    float xv[16] = {a.x, a.y, a.z, a.w, b.x, b.y, b.z, b.w,
                    c.x, c.y, c.z, c.w, d.x, d.y, d.z, d.w};
    unsigned short h8[8], l8[8];
    #pragma unroll
    for (int j = 0; j < 8; j++) split_bf16(fmaxf(xv[j], 0.f), h8[j], l8[j]);
    *(bfrag*)&WAH[row][col] = *(bfrag*)h8;
    *(bfrag*)&WAL[row][col] = *(bfrag*)l8;
    #pragma unroll
    for (int j = 0; j < 8; j++) split_bf16(fmaxf(xv[8 + j], 0.f), h8[j], l8[j]);
    *(bfrag*)&WAH[row][col + 8] = *(bfrag*)h8;
    *(bfrag*)&WAL[row][col + 8] = *(bfrag*)l8;
}

// TOK=80 (5 m-frags): tile count <= 224 <= 256 for ANY type distribution,
// so every block runs in the first (and only) wave of blocks per CU.
__global__ __launch_bounds__(TPB_MAIN, 2)
void angle_main(const float* __restrict__ s, const float* __restrict__ si,
                const float* __restrict__ b_in, const float* __restrict__ b_init2,
                const float* __restrict__ bb1, const float* __restrict__ bb2,
                const float* __restrict__ Wout, const float* __restrict__ b_out,
                const int* __restrict__ aatype,
                const int* __restrict__ wsI, const unsigned short* __restrict__ wt,
                float* __restrict__ out)
{
    // LDS pool: two (Ah,Al) buffers of [80][136] u16; epilogue Hf/Of overlap.
    #define ABUF 21760
    __shared__ __align__(16) char pool[4 * ABUF];
    __shared__ int ptok[TOK];
    __shared__ int cntS[E_TYPES];

    arr136 AH0 = (arr136)(pool);
    arr136 AL0 = (arr136)(pool + ABUF);
    arr136 AH1 = (arr136)(pool + 2 * ABUF);
    arr136 AL1 = (arr136)(pool + 3 * ABUF);
    float (*Hf)[132] = (float (*)[132])(pool);            // 80*132*4 = 42240 <= 2*ABUF
    float (*Of)[16]  = (float (*)[16])(pool + 2 * ABUF);  // 5KB

    int t = threadIdx.x;
    int w = t >> 6, lane = t & 63;
    int lane15 = lane & 15, quad = lane >> 4;

    // XCD-chunked bijective swizzle (e-sorted tiles -> per-XCD L2 residency).
    int bid = blockIdx.x;
    const int q = MAX_TILES >> 3, r = MAX_TILES & 7;   // 28, 0
    int xcd = bid & 7, sub = bid >> 3;
    int tile = (xcd < r ? xcd * (q + 1) : r * (q + 1) + (xcd - r) * q) + sub;

    // wave0: per-type totals from the 64x20 chunk histograms
    if (w == 0 && lane < E_TYPES) {
        int c = 0;
        #pragma unroll
        for (int b = 0; b < NPREP; b++) c += wsI[HIST_OFF + b * E_TYPES + lane];
        cntS[lane] = c;
    }
    __syncthreads();

    int pos = tile * TOK;
    int e = -1, poff_e = 0;
    {
        int accT = 0;
        #pragma unroll
        for (int ee = 0; ee < E_TYPES; ee++) {
            int pad = ((cntS[ee] + TOK - 1) / TOK) * TOK;   // TOK not pow2
            if (e < 0 && pos < accT + pad) { e = ee; poff_e = accT; }
            accT += pad;
        }
        if (pos >= accT) return;     // uniform exit (all waves agree)
    }
    int pos_in = pos - poff_e;
    int n = cntS[e] - pos_in; if (n > TOK) n = TOK;

    int nc = w * 16 + lane15;
    const bfrag* wt1 = (const bfrag*)((const char*)wt + WT1_OFF);
    const bfrag* wtr = (const bfrag*)((const char*)wt + WTR_OFF);
    size_t wb = (size_t)(e * 8 + w) * 24;

    // Early issue: stage-0 weights + all bias values (overlap the rank-scan).
    bfrag Wr0[8], Wr1[8];
    LOADW(Wr0, wt1 + wb * 128 + lane);
    float bv_in = b_in[e * CH + nc] + b_init2[e * CH + nc];
    float bvb1a = bb1[(e * NBLK + 0) * CH + nc];
    float bvb1b = bb1[(e * NBLK + 1) * CH + nc];
    float bvb2a = bb2[(e * NBLK + 0) * CH + nc];
    float bvb2b = bb2[(e * NBLK + 1) * CH + nc];

    // wave0: rank-scan aatype -> ptok (tokens with rank [pos_in, pos_in+n))
    if (w == 0) {
        int hb = wsI[HIST_OFF + lane * E_TYPES + e];
        int inc = hb;
        #pragma unroll
        for (int d = 1; d < 64; d <<= 1) { int v = __shfl_up(inc, d); if (lane >= d) inc += v; }
        int pre = inc - hb;
        unsigned long long mle = __ballot(pre <= pos_in);
        int cb = 63 - __clzll(mle);
        int running = __shfl(pre, cb);
        int base = cb * 256;
        int lim = pos_in + n;
        while (running < lim && base < N_TOK) {
            const int4 a4 = *(const int4*)&aatype[base + lane * 4];
            int m0 = (a4.x == e), m1 = (a4.y == e), m2 = (a4.z == e), m3 = (a4.w == e);
            int c = m0 + m1 + m2 + m3;
            int incl = c;
            #pragma unroll
            for (int d = 1; d < 64; d <<= 1) { int v = __shfl_up(incl, d); if (lane >= d) incl += v; }
            int rk = running + incl - c;
            int tk = base + lane * 4;
            if (m0) { if (rk >= pos_in && rk < lim) ptok[rk - pos_in] = tk;     rk++; }
            if (m1) { if (rk >= pos_in && rk < lim) ptok[rk - pos_in] = tk + 1; rk++; }
            if (m2) { if (rk >= pos_in && rk < lim) ptok[rk - pos_in] = tk + 2; rk++; }
            if (m3) { if (rk >= pos_in && rk < lim) ptok[rk - pos_in] = tk + 3; rk++; }
            running += __shfl(incl, 63);
            base += 256;
        }
        int t0v = ptok[0];
        for (int i = n + lane; i < TOK; i += 64) ptok[i] = t0v;   // pad w/ dup token
    }
    __syncthreads();

    // ---- phase 1: h = [relu(s) relu(si)] @ [Win;Winit] + biases, K=768 ----
    // Staging: 640 segs (80 rows x 8) over 512 threads; waves 0-1 take a
    // second seg (wave-uniform). One chunk prefetched ahead in regs.
    int srow0 = t >> 3;
    int scol0 = (t & 7) * 16;
    bool has2 = (t < TOK * 8 - TPB_MAIN);    // t < 128
    int srow1 = srow0 + 64;
    size_t ro0 = (size_t)ptok[srow0] * CS + scol0;
    size_t ro1 = has2 ? ((size_t)ptok[srow1] * CS + scol0) : ro0;
    float4 p0 = *(const float4*)(s + ro0);
    float4 p1 = *(const float4*)(s + ro0 + 4);
    float4 p2 = *(const float4*)(s + ro0 + 8);
    float4 p3 = *(const float4*)(s + ro0 + 12);
    float4 q0, q1, q2, q3;
    if (has2) {
        q0 = *(const float4*)(s + ro1);
        q1 = *(const float4*)(s + ro1 + 4);
        q2 = *(const float4*)(s + ro1 + 8);
        q3 = *(const float4*)(s + ro1 + 12);
    }

    f32x4 aA[MFRAG], aB[MFRAG];
    #pragma unroll
    for (int m = 0; m < MFRAG; m++) {
        aA[m] = (f32x4){bv_in, bv_in, bv_in, bv_in};
        aB[m] = (f32x4){0.f, 0.f, 0.f, 0.f};
    }

    #pragma unroll
    for (int c = 0; c < 6; c++) {
        arr136 WAH = (c & 1) ? AH1 : AH0;
        arr136 WAL = (c & 1) ? AL1 : AL0;
        stage_seg(WAH, WAL, srow0, scol0, p0, p1, p2, p3);
        if (has2) stage_seg(WAH, WAL, srow1, scol0, q0, q1, q2, q3);
        if (c < 5) {   // prefetch next chunk activations
            const float* src = (c + 1 < 3) ? s : si;
            int kb0 = ((c + 1 < 3) ? (c + 1) : (c - 2)) * KC;
            p0 = *(const float4*)(src + ro0 + kb0);
            p1 = *(const float4*)(src + ro0 + kb0 + 4);
            p2 = *(const float4*)(src + ro0 + kb0 + 8);
            p3 = *(const float4*)(src + ro0 + kb0 + 12);
            if (has2) {
                q0 = *(const float4*)(src + ro1 + kb0);
                q1 = *(const float4*)(src + ro1 + kb0 + 4);
                q2 = *(const float4*)(src + ro1 + kb0 + 8);
                q3 = *(const float4*)(src + ro1 + kb0 + 12);
            }
        }
        __syncthreads();
        if ((c & 1) == 0) {
            if (c < 5) LOADW(Wr1, wt1 + (wb + (c + 1) * 4) * 128 + lane);
            MFMA_STAGE(AH0, AL0, Wr0, aA, aB);
        } else {
            if (c == 5) LOADW(Wr0, wtr + (((size_t)(e * 4) * 8 + w) * 4) * 128 + lane);
            else        LOADW(Wr0, wt1 + (wb + (c + 1) * 4) * 128 + lane);
            MFMA_STAGE(AH1, AL1, Wr1, aA, aB);
        }
    }

    // ---- residual blocks: 4 GEMMs, one barrier each ----
    f32x4 h[MFRAG];
    #pragma unroll
    for (int m = 0; m < MFRAG; m++) h[m] = aA[m] + aB[m];
    WRITE_H(AH0, AL0, h);
    __syncthreads();

    f32x4 rA[MFRAG], rB[MFRAG];
    // g0: a1 = relu(h) @ W1[0] + bb1[0]
    #pragma unroll
    for (int m = 0; m < MFRAG; m++) {
        rA[m] = (f32x4){bvb1a, bvb1a, bvb1a, bvb1a};
        rB[m] = (f32x4){0.f, 0.f, 0.f, 0.f};
    }
    LOADW(Wr1, wtr + (((size_t)(e * 4 + 1) * 8 + w) * 4) * 128 + lane);
    MFMA_STAGE(AH0, AL0, Wr0, rA, rB);
    #pragma unroll
    for (int m = 0; m < MFRAG; m++) rA[m] += rB[m];
    WRITE_H(AH1, AL1, rA);
    __syncthreads();

    // g1: h += relu(a1) @ W2[0] + bb2[0]
    #pragma unroll
    for (int m = 0; m < MFRAG; m++) {
        rA[m] = (f32x4){bvb2a, bvb2a, bvb2a, bvb2a};
        rB[m] = (f32x4){0.f, 0.f, 0.f, 0.f};
    }
    LOADW(Wr0, wtr + (((size_t)(e * 4 + 2) * 8 + w) * 4) * 128 + lane);
    MFMA_STAGE(AH1, AL1, Wr1, rA, rB);
    #pragma unroll
    for (int m = 0; m < MFRAG; m++) h[m] += rA[m] + rB[m];
    WRITE_H(AH0, AL0, h);
    __syncthreads();

    // g2: a1 = relu(h) @ W1[1] + bb1[1]
    #pragma unroll
    for (int m = 0; m < MFRAG; m++) {
        rA[m] = (f32x4){bvb1b, bvb1b, bvb1b, bvb1b};
        rB[m] = (f32x4){0.f, 0.f, 0.f, 0.f};
    }
    LOADW(Wr1, wtr + (((size_t)(e * 4 + 3) * 8 + w) * 4) * 128 + lane);
    MFMA_STAGE(AH0, AL0, Wr0, rA, rB);
    #pragma unroll
    for (int m = 0; m < MFRAG; m++) rA[m] += rB[m];
    WRITE_H(AH1, AL1, rA);
    __syncthreads();

    // g3: h += relu(a1) @ W2[1] + bb2[1]
    #pragma unroll
    for (int m = 0; m < MFRAG; m++) {
        rA[m] = (f32x4){bvb2b, bvb2b, bvb2b, bvb2b};
        rB[m] = (f32x4){0.f, 0.f, 0.f, 0.f};
    }
    MFMA_STAGE(AH1, AL1, Wr1, rA, rB);
    #pragma unroll
    for (int m = 0; m < MFRAG; m++) h[m] += rA[m] + rB[m];

    // ---- epilogue: relu(h) fp32 -> Hf (buf0 region; g3 readers used buf1) ----
    #pragma unroll
    for (int m = 0; m < MFRAG; m++)
    {
        #pragma unroll
        for (int rr = 0; rr < 4; rr++)
            Hf[m * 16 + quad * 4 + rr][nc] = fmaxf(h[m][rr], 0.f);
    }
    __syncthreads();

    // ---- out = relu(h) @ Wout + b_out (128 -> 14), 4-way partials ----
    const float* WoutE = Wout + (size_t)e * CH * (NANG * 2);
    const float* boutE = b_out + (size_t)e * (NANG * 2);
    for (int idx = t; idx < n * (NANG * 2); idx += TPB_MAIN) {
        int i = idx / (NANG * 2);
        int o = idx - i * (NANG * 2);
        float v0 = boutE[o], v1 = 0.f, v2 = 0.f, v3 = 0.f;
        #pragma unroll 4
        for (int k = 0; k < CH; k += 4) {
            v0 = fmaf(Hf[i][k],     WoutE[(size_t)k * (NANG * 2) + o],       v0);
            v1 = fmaf(Hf[i][k + 1], WoutE[(size_t)(k + 1) * (NANG * 2) + o], v1);
            v2 = fmaf(Hf[i][k + 2], WoutE[(size_t)(k + 2) * (NANG * 2) + o], v2);
            v3 = fmaf(Hf[i][k + 3], WoutE[(size_t)(k + 3) * (NANG * 2) + o], v3);
        }
        Of[i][o] = (v0 + v1) + (v2 + v3);
    }
    __syncthreads();

    // ---- pair-normalize and store ----
    for (int idx = t; idx < n * NANG; idx += TPB_MAIN) {
        int i = idx / NANG;
        int a = idx - i * NANG;
        float x = Of[i][2 * a];
        float y = Of[i][2 * a + 1];
        float nr = fmaxf(sqrtf(x * x + y * y), 1e-12f);
        size_t base = (size_t)ptok[i] * (NANG * 2) + 2 * a;
        out[base]     = x / nr;
        out[base + 1] = y / nr;
    }
}

extern "C" void kernel_launch(void* const* d_in, const int* in_sizes, int n_in,
                              void* d_out, int out_size, void* d_ws, size_t ws_size,
                              hipStream_t stream) {
    const float* s       = (const float*)d_in[0];
    const float* s_init  = (const float*)d_in[1];
    const int*   aatype  = (const int*)d_in[2];
    const float* Win     = (const float*)d_in[3];
    const float* b_in    = (const float*)d_in[4];
    const float* Winit   = (const float*)d_in[5];
    const float* b_init2 = (const float*)d_in[6];
    const float* Wb1     = (const float*)d_in[7];
    const float* bb1     = (const float*)d_in[8];
    const float* Wb2     = (const float*)d_in[9];
    const float* bb2     = (const float*)d_in[10];
    const float* Wout    = (const float*)d_in[11];
    const float* b_out   = (const float*)d_in[12];
    int* wsI = (int*)d_ws;
    unsigned short* wt = (unsigned short*)d_ws;
    float* out = (float*)d_out;

    hipLaunchKernelGGL(prep1, dim3(1664), dim3(256), 0, stream,
                       Win, Winit, Wb1, Wb2, aatype, wsI, wt);
    hipLaunchKernelGGL(angle_main, dim3(MAX_TILES), dim3(TPB_MAIN), 0, stream,
                       s, s_init, b_in, b_init2, bb1, bb2, Wout, b_out,
                       aatype, wsI, wt, out);
}